// Round 2
// baseline (783.409 us; speedup 1.0000x reference)
//
#include <hip/hip_runtime.h>

// EquivariantLayerNorm: N rows of DIM=480 fp32.
//  [0,128)   : standard LayerNorm over 128 with weight+bias
//  [128,320) : 64 segments x 3, per-segment mean/var norm (no affine)
//  [320,480) : 32 segments x 5, per-segment mean/var norm (no affine)
//
// R2 structure: 4 rows per 256-thread block, staged through LDS so that ALL
// global traffic is contiguous float4 (the stride-3/5 segment scatter happens
// in LDS, where odd strides are bank-conflict-free). One wave per row for the
// compute phase.

constexpr int N_ROWS = 262144;
constexpr int S = 128;
constexpr int MUL1 = 64, D1 = 3;
constexpr int MUL2 = 32, D2 = 5;
constexpr int DIM = S + MUL1 * D1 + MUL2 * D2; // 480
constexpr float EPS = 1e-5f;
constexpr int ROWS_PER_BLOCK = 4;
constexpr int TILE_F4 = ROWS_PER_BLOCK * DIM / 4; // 480 float4

__global__ __launch_bounds__(256) void eqln_kernel(
    const float* __restrict__ x,
    const float* __restrict__ weight,
    const float* __restrict__ bias,
    float* __restrict__ out)
{
    __shared__ float tile[ROWS_PER_BLOCK * DIM]; // 7680 B, 16B-aligned rows (1920 B each)

    const long long block_row = (long long)blockIdx.x * ROWS_PER_BLOCK;

    // ---- Phase 1: coalesced global -> LDS (float4) ----
    {
        const float4* __restrict__ x4 = (const float4*)(x + block_row * DIM);
        float4* t4 = (float4*)tile;
#pragma unroll
        for (int i = threadIdx.x; i < TILE_F4; i += 256) t4[i] = x4[i];
    }
    __syncthreads();

    // ---- Phase 2: per-wave row compute, in-place in LDS ----
    const int wave = threadIdx.x >> 6;   // row within tile
    const int lane = threadIdx.x & 63;
    float* r = tile + wave * DIM;

    // scalar LayerNorm over [0,128): lane i owns elements i and i+64
    // (stride-1 dword LDS reads: bank = i%32, 2 lanes/bank -> free)
    {
        float a0 = r[lane];
        float a1 = r[lane + 64];
        float s  = a0 + a1;
        float sq = a0 * a0 + a1 * a1;
#pragma unroll
        for (int off = 32; off >= 1; off >>= 1) {
            s  += __shfl_xor(s,  off, 64);
            sq += __shfl_xor(sq, off, 64);
        }
        const float m   = s * (1.0f / 128.0f);
        const float var = sq * (1.0f / 128.0f) - m * m;
        const float rs  = rsqrtf(var + EPS);
        // weight/bias: scalar loads, L1-resident across all rows
        r[lane]      = (a0 - m) * rs * weight[lane]      + bias[lane];
        r[lane + 64] = (a1 - m) * rs * weight[lane + 64] + bias[lane + 64];
    }

    // v1: 64 segments of 3, lane i = segment i (stride 3 coprime 32 -> conflict-free)
    {
        float* p = r + S + 3 * lane;
        float a0 = p[0], a1 = p[1], a2 = p[2];
        float mm = (a0 + a1 + a2) * (1.0f / 3.0f);
        float d0 = a0 - mm, d1 = a1 - mm, d2 = a2 - mm;
        float vv = (d0 * d0 + d1 * d1 + d2 * d2) * (1.0f / 3.0f);
        float rr = rsqrtf(vv + EPS);
        p[0] = d0 * rr;
        p[1] = d1 * rr;
        p[2] = d2 * rr;
    }

    // v2: 32 segments of 5, lanes 0..31 (stride 5 coprime 32 -> conflict-free)
    if (lane < 32) {
        float* p = r + S + MUL1 * D1 + 5 * lane;
        float a[5];
#pragma unroll
        for (int i = 0; i < 5; ++i) a[i] = p[i];
        float ssum = 0.0f;
#pragma unroll
        for (int i = 0; i < 5; ++i) ssum += a[i];
        float mm = ssum * 0.2f;
        float vv = 0.0f;
#pragma unroll
        for (int i = 0; i < 5; ++i) { float d = a[i] - mm; vv += d * d; }
        vv *= 0.2f;
        float rr = rsqrtf(vv + EPS);
#pragma unroll
        for (int i = 0; i < 5; ++i) p[i] = (a[i] - mm) * rr;
    }
    __syncthreads();

    // ---- Phase 3: coalesced LDS -> global (float4) ----
    {
        float4* __restrict__ o4 = (float4*)(out + block_row * DIM);
        const float4* t4 = (const float4*)tile;
#pragma unroll
        for (int i = threadIdx.x; i < TILE_F4; i += 256) o4[i] = t4[i];
    }
}

extern "C" void kernel_launch(void* const* d_in, const int* in_sizes, int n_in,
                              void* d_out, int out_size, void* d_ws, size_t ws_size,
                              hipStream_t stream) {
    const float* x      = (const float*)d_in[0];
    const float* weight = (const float*)d_in[1];
    const float* bias   = (const float*)d_in[2];
    float* out = (float*)d_out;

    dim3 grid(N_ROWS / ROWS_PER_BLOCK);  // 65536
    dim3 block(256);
    eqln_kernel<<<grid, block, 0, stream>>>(x, weight, bias, out);
}